// Round 1
// baseline (484.215 us; speedup 1.0000x reference)
//
#include <hip/hip_runtime.h>

// PointPillarScatter: out[b, c, y, x] = feat[p, c] where pillar p sits at (b, y, x), else 0.
// Grid: NX=432, NY=496, NZ=1, C=64, B=8 (B derived from out_size).
// Approach: inverse map (cell -> pillar index) in d_ws, then a single fully-coalesced
// gather pass that writes every output element exactly once (zero or feature).

#define NXC   432
#define NYC   496
#define CCH   64
#define PLANE (NXC * NYC)        // 214272 cells per (batch, channel) plane
#define CELLS_PER_BLOCK 64       // PLANE % 64 == 0 (214272 = 3348 * 64)

__global__ __launch_bounds__(256) void init_map_kernel(int* __restrict__ map, int n4) {
    int i = blockIdx.x * blockDim.x + threadIdx.x;
    if (i < n4) {
        ((int4*)map)[i] = make_int4(-1, -1, -1, -1);
    }
}

__global__ __launch_bounds__(256) void scatter_idx_kernel(const int* __restrict__ coords,
                                                          int* __restrict__ map, int P) {
    int p = blockIdx.x * blockDim.x + threadIdx.x;
    if (p < P) {
        int4 c = ((const int4*)coords)[p];   // [b, z, y, x]
        int flat = c.x * PLANE + (c.y + c.z * NXC + c.w);  // z term is 0 (NZ=1) but kept per ref
        map[flat] = p;
    }
}

// Block = 64 cells x 64 channels. lane = cell offset (0..63), q = tid/64 -> channels [16q, 16q+16).
// Each thread: 1 map read, 4 float4 gathers from one 64B line of feat, 16 coalesced dword stores
// (for fixed channel, 64 lanes store 64 consecutive floats = 256B contiguous).
__global__ __launch_bounds__(256) void gather_kernel(const float* __restrict__ feat,
                                                     const int* __restrict__ map,
                                                     float* __restrict__ out) {
    const int tid  = threadIdx.x;
    const int lane = tid & 63;
    const int q    = tid >> 6;                       // 0..3
    const int cb   = blockIdx.x % (PLANE / CELLS_PER_BLOCK);
    const int b    = blockIdx.x / (PLANE / CELLS_PER_BLOCK);
    const int cell = cb * CELLS_PER_BLOCK + lane;

    const int p = map[(long)b * PLANE + cell];

    float4 v0 = make_float4(0.f, 0.f, 0.f, 0.f);
    float4 v1 = v0, v2 = v0, v3 = v0;
    if (p >= 0) {
        const float4* src = (const float4*)(feat + (long)p * CCH + q * 16);
        v0 = src[0];
        v1 = src[1];
        v2 = src[2];
        v3 = src[3];
    }

    float* o = out + (long)(b * CCH + q * 16) * PLANE + cell;
    o[0L  * PLANE] = v0.x;
    o[1L  * PLANE] = v0.y;
    o[2L  * PLANE] = v0.z;
    o[3L  * PLANE] = v0.w;
    o[4L  * PLANE] = v1.x;
    o[5L  * PLANE] = v1.y;
    o[6L  * PLANE] = v1.z;
    o[7L  * PLANE] = v1.w;
    o[8L  * PLANE] = v2.x;
    o[9L  * PLANE] = v2.y;
    o[10L * PLANE] = v2.z;
    o[11L * PLANE] = v2.w;
    o[12L * PLANE] = v3.x;
    o[13L * PLANE] = v3.y;
    o[14L * PLANE] = v3.z;
    o[15L * PLANE] = v3.w;
}

extern "C" void kernel_launch(void* const* d_in, const int* in_sizes, int n_in,
                              void* d_out, int out_size, void* d_ws, size_t ws_size,
                              hipStream_t stream) {
    const float* x0     = (const float*)d_in[0];
    const int*   coords = (const int*)d_in[1];
    float*       out    = (float*)d_out;

    const int P = in_sizes[0] / CCH;                 // 128000 pillars
    const int B = out_size / (CCH * PLANE);          // 8

    int* map = (int*)d_ws;                           // B*PLANE int32 = 6.86 MB scratch

    // 1) init map to -1 (vectorized int4)
    const int n4 = (B * PLANE) / 4;
    init_map_kernel<<<(n4 + 255) / 256, 256, 0, stream>>>(map, n4);

    // 2) scatter pillar index into map
    scatter_idx_kernel<<<(P + 255) / 256, 256, 0, stream>>>(coords, map, P);

    // 3) gather pass: write full output, fully coalesced
    const int nblocks = B * (PLANE / CELLS_PER_BLOCK);   // 26784
    gather_kernel<<<nblocks, 256, 0, stream>>>(x0, map, out);
}

// Round 2
// 475.168 us; speedup vs baseline: 1.0190x; 1.0190x over previous
//
#include <hip/hip_runtime.h>

// PointPillarScatter: out[b, c, y, x] = feat[p, c] where pillar p sits at (b, y, x), else 0.
// NX=432, NY=496, NZ=1, C=64, B=8 (B derived from out_size).
// Inverse-map approach: cell -> pillar index map in d_ws, then one fully-coalesced
// gather pass writing every output element exactly once (zero or feature).

#define NXC   432
#define NYC   496
#define CCH   64
#define PLANE (NXC * NYC)        // 214272 cells per (batch, channel) plane
#define CB    256                // cells per gather block; PLANE % 256 == 0 (214272 = 837*256)

__global__ __launch_bounds__(256) void init_map_kernel(int* __restrict__ map, int n4) {
    int i = blockIdx.x * blockDim.x + threadIdx.x;
    if (i < n4) {
        ((int4*)map)[i] = make_int4(-1, -1, -1, -1);
    }
}

__global__ __launch_bounds__(256) void scatter_idx_kernel(const int* __restrict__ coords,
                                                          int* __restrict__ map, int P) {
    int p = blockIdx.x * blockDim.x + threadIdx.x;
    if (p < P) {
        int4 c = ((const int4*)coords)[p];   // [b, z, y, x]
        int flat = c.x * PLANE + (c.y + c.z * NXC + c.w);  // z term is 0 (NZ=1)
        map[flat] = p;
    }
}

// Block = 256 cells x 64 channels. lane l (0..63) owns cells [4l, 4l+4); wave w (0..3)
// owns channels [16w, 16w+16). Per thread: one coalesced int4 map load, up to 16 float4
// feat loads (one 64B row-quarter per occupied cell), 16 float4 stores — each wave store
// instruction covers 1 KB contiguous output.
__global__ __launch_bounds__(256) void gather_kernel(const float* __restrict__ feat,
                                                     const int* __restrict__ map,
                                                     float* __restrict__ out) {
    const int tid   = threadIdx.x;
    const int w     = tid >> 6;                      // wave id -> channel group
    const int l     = tid & 63;                      // lane -> cell group
    const int bpb   = PLANE / CB;                    // 837 blocks per batch
    const int cb    = blockIdx.x % bpb;
    const int b     = blockIdx.x / bpb;
    const int cell0 = cb * CB;

    // coalesced map read: 64 lanes x int4 = 1 KB (waves redundantly read, L1-hit)
    const int4 pm = ((const int4*)(map + (long)b * PLANE + cell0))[l];
    const int pidx[4] = { pm.x, pm.y, pm.z, pm.w };

    float v[4][16];                                  // [cell][channel], register-resident
    #pragma unroll
    for (int i = 0; i < 4; ++i) {
        const int p = pidx[i];
        if (p >= 0) {
            const float4* src = (const float4*)(feat + (long)p * CCH + w * 16);
            float4 a0 = src[0], a1 = src[1], a2 = src[2], a3 = src[3];
            v[i][0]  = a0.x; v[i][1]  = a0.y; v[i][2]  = a0.z; v[i][3]  = a0.w;
            v[i][4]  = a1.x; v[i][5]  = a1.y; v[i][6]  = a1.z; v[i][7]  = a1.w;
            v[i][8]  = a2.x; v[i][9]  = a2.y; v[i][10] = a2.z; v[i][11] = a2.w;
            v[i][12] = a3.x; v[i][13] = a3.y; v[i][14] = a3.z; v[i][15] = a3.w;
        } else {
            #pragma unroll
            for (int c = 0; c < 16; ++c) v[i][c] = 0.f;
        }
    }

    // transpose in registers and store: channel c -> float4 over 4 consecutive cells
    float* o = out + (long)(b * CCH + w * 16) * PLANE + cell0 + 4 * l;
    #pragma unroll
    for (int c = 0; c < 16; ++c) {
        float4 s = make_float4(v[0][c], v[1][c], v[2][c], v[3][c]);
        *(float4*)(o + (long)c * PLANE) = s;
    }
}

extern "C" void kernel_launch(void* const* d_in, const int* in_sizes, int n_in,
                              void* d_out, int out_size, void* d_ws, size_t ws_size,
                              hipStream_t stream) {
    const float* x0     = (const float*)d_in[0];
    const int*   coords = (const int*)d_in[1];
    float*       out    = (float*)d_out;

    const int P = in_sizes[0] / CCH;                 // 128000 pillars
    const int B = out_size / (CCH * PLANE);          // 8

    int* map = (int*)d_ws;                           // B*PLANE int32 = 6.86 MB scratch

    // 1) init map to -1
    const int n4 = (B * PLANE) / 4;
    init_map_kernel<<<(n4 + 255) / 256, 256, 0, stream>>>(map, n4);

    // 2) scatter pillar index into map
    scatter_idx_kernel<<<(P + 255) / 256, 256, 0, stream>>>(coords, map, P);

    // 3) gather pass: write full output, fully coalesced, float4-wide
    const int nblocks = B * (PLANE / CB);            // 6696
    gather_kernel<<<nblocks, 256, 0, stream>>>(x0, map, out);
}

// Round 4
// 467.886 us; speedup vs baseline: 1.0349x; 1.0156x over previous
//
#include <hip/hip_runtime.h>

// PointPillarScatter: out[b, c, y, x] = feat[p, c] where pillar p sits at (b, y, x), else 0.
// NX=432, NY=496, NZ=1, C=64, B=8 (B derived from out_size).
// Inverse-map approach: cell -> pillar index map in d_ws, then one fully-coalesced
// gather pass writing every output element exactly once (zero or feature).
// R4: channel-chunked gather (4ch at a time) for lower VGPR / better pipelining,
//     nontemporal output stores (via ext_vector_type -- HIP float4 struct is
//     rejected by __builtin_nontemporal_store) to keep L2 for random feat reads.

#define NXC   432
#define NYC   496
#define CCH   64
#define PLANE (NXC * NYC)        // 214272 cells per (batch, channel) plane
#define CB    256                // cells per gather block; 214272 = 837 * 256

typedef float vfloat4 __attribute__((ext_vector_type(4)));

__global__ __launch_bounds__(256) void init_map_kernel(int* __restrict__ map, int n4) {
    int i = blockIdx.x * blockDim.x + threadIdx.x;
    if (i < n4) {
        ((int4*)map)[i] = make_int4(-1, -1, -1, -1);
    }
}

__global__ __launch_bounds__(256) void scatter_idx_kernel(const int* __restrict__ coords,
                                                          int* __restrict__ map, int P) {
    int p = blockIdx.x * blockDim.x + threadIdx.x;
    if (p < P) {
        int4 c = ((const int4*)coords)[p];   // [b, z, y, x]
        int flat = c.x * PLANE + (c.y + c.z * NXC + c.w);  // z term is 0 (NZ=1)
        map[flat] = p;
    }
}

// Block = 256 cells x 64 channels. Wave w (0..3) owns channels [16w, 16w+16),
// lane l (0..63) owns cells [4l, 4l+4). Channels processed in 4 chunks of 4:
// per chunk, up to 4 vfloat4 feat loads (one per occupied cell), 4x4 register
// transpose, 4 nontemporal vfloat4 stores (1 KB contiguous per wave store instr).
__global__ __launch_bounds__(256) void gather_kernel(const float* __restrict__ feat,
                                                     const int* __restrict__ map,
                                                     float* __restrict__ out, int P) {
    const int tid   = threadIdx.x;
    const int w     = tid >> 6;                      // wave -> channel group base 16w
    const int l     = tid & 63;                      // lane -> cell group
    const int bpb   = PLANE / CB;                    // 837 blocks per batch
    const int cb    = blockIdx.x % bpb;
    const int b     = blockIdx.x / bpb;
    const int cell0 = cb * CB;

    // coalesced map read: 64 lanes x int4 = 1 KB (waves share lines via L1)
    const int4 pm = ((const int4*)(map + (long)b * PLANE + cell0))[l];
    const int pidx[4] = { pm.x, pm.y, pm.z, pm.w };
    const unsigned uP = (unsigned)P;

    const float* fbase = feat + (long)(w * 16);
    float*       obase = out + (long)(b * CCH + w * 16) * PLANE + cell0 + 4 * l;

    #pragma unroll
    for (int k = 0; k < 4; ++k) {                    // channel chunk: 16w+4k .. +3
        vfloat4 s0 = (vfloat4)(0.f);
        vfloat4 s1 = s0, s2 = s0, s3 = s0;
        if ((unsigned)pidx[0] < uP) s0 = *(const vfloat4*)(fbase + (long)pidx[0] * CCH + k * 4);
        if ((unsigned)pidx[1] < uP) s1 = *(const vfloat4*)(fbase + (long)pidx[1] * CCH + k * 4);
        if ((unsigned)pidx[2] < uP) s2 = *(const vfloat4*)(fbase + (long)pidx[2] * CCH + k * 4);
        if ((unsigned)pidx[3] < uP) s3 = *(const vfloat4*)(fbase + (long)pidx[3] * CCH + k * 4);

        float* o = obase + (long)(k * 4) * PLANE;
        vfloat4 t0 = { s0.x, s1.x, s2.x, s3.x };
        vfloat4 t1 = { s0.y, s1.y, s2.y, s3.y };
        vfloat4 t2 = { s0.z, s1.z, s2.z, s3.z };
        vfloat4 t3 = { s0.w, s1.w, s2.w, s3.w };
        __builtin_nontemporal_store(t0, (vfloat4*)(o));
        __builtin_nontemporal_store(t1, (vfloat4*)(o + 1L * PLANE));
        __builtin_nontemporal_store(t2, (vfloat4*)(o + 2L * PLANE));
        __builtin_nontemporal_store(t3, (vfloat4*)(o + 3L * PLANE));
    }
}

extern "C" void kernel_launch(void* const* d_in, const int* in_sizes, int n_in,
                              void* d_out, int out_size, void* d_ws, size_t ws_size,
                              hipStream_t stream) {
    const float* x0     = (const float*)d_in[0];
    const int*   coords = (const int*)d_in[1];
    float*       out    = (float*)d_out;

    const int P = in_sizes[0] / CCH;                 // 128000 pillars
    const int B = out_size / (CCH * PLANE);          // 8

    int* map = (int*)d_ws;                           // B*PLANE int32 = 6.86 MB scratch

    // 1) init map to -1 (any value with (unsigned)v >= P marks empty)
    const int n4 = (B * PLANE) / 4;
    init_map_kernel<<<(n4 + 255) / 256, 256, 0, stream>>>(map, n4);

    // 2) scatter pillar index into map
    scatter_idx_kernel<<<(P + 255) / 256, 256, 0, stream>>>(coords, map, P);

    // 3) gather pass: write full output, fully coalesced, float4-wide, nontemporal
    const int nblocks = B * (PLANE / CB);            // 6696
    gather_kernel<<<nblocks, 256, 0, stream>>>(x0, map, out, P);
}